// Round 19
// baseline (289.630 us; speedup 1.0000x reference)
//
#include <hip/hip_runtime.h>
#include <hip/hip_bf16.h>
#include <hip/hip_fp16.h>

// NAM_89739046683406: per-feature tiny MLP (B=32768, F=128, H=64)
// logit(b) = bias + sum_f [ relu(relu(x[b,f]*w1[f]+b1[f]) @ w2[f] + b2[f]) . w3[f] + b3[f] ]
// out = [1-sigmoid, sigmoid]
//
// R40 = R39 body (fdot2 dual-acc + setprio; main plateaued ~48.8us) with
// the SECOND DISPATCH ELIMINATED: total-main has been a constant 63-68us
// across all passing rounds; nam_final (4MB partial read, 128-block
// launch) + 1 dispatch boundary is the kernel-controllable slice (~6-8us).
//   - part[32][B] (4MB) -> logitacc[B] (128KB): each block atomicAdds its
//     512 row-sums (device-scope default, cross-XCD safe; 32 adds/address).
//   - per-rg completion counter cnt[64]: threadfence-reduction pattern
//     (atomics -> __threadfence -> __syncthreads -> acq-rel fetch_add);
//     the 32nd finisher block does bias+sigmoid+store for its 512 rows
//     via agent-scope acquire loads. No spin-waits -> no deadlock.
//   - ws re-zeroed by one hipMemsetAsync in kernel_launch (stream op,
//     graph-capturable; harness itself uses async memsets).
//   - fp32 atomic reassociation ~1e-6 << 0.0194 threshold.
//
// Evidence ledger (19 rounds):
//   - WINS: R22 f16 pk-math (-15%); R33 fdot2 (-4%); R37 setprio (-3%).
//   - main-side classes ALL CLOSED: occupancy (R24/R26/R27/R34), ILP-
//     pipelining (R23/R35), chunk-size (R38 soft-spills), x-path (R23/R25),
//     tail scatter (R28/R36), MFMA-epilogue (R30/R31), fdot2 chain split
//     (R39 neutral).
//   - NO float-ext-vector arrays + __builtin_elementwise_* (R17/R18).
//   - Judge spills by FETCH/WRITE counters, not VGPR_Count.
// Failure signatures THIS round: absmax blowup = visibility bug -> revert
// R37; total ~114 unchanged = out-of-main is pure harness overhead ->
// revert R37 and conclude plateau.

#define B_SZ 32768
#define F_SZ 128
#define H_SZ 64

typedef _Float16 half8 __attribute__((ext_vector_type(8)));  // f16 x8 (4 VGPR)
typedef float floatx4 __attribute__((ext_vector_type(4)));   // fp32 x4 acc

union U8 { half8 v; unsigned u[4]; };

// pack two fp32 -> half2 bits (RNE)
__device__ __forceinline__ unsigned pkh(float lo, float hi) {
    __half2 h = __float22half2_rn(make_float2(lo, hi));
    return __builtin_bit_cast(unsigned, h);
}

// pack two fp32 -> half2 bits (RTZ, single v_cvt_pkrtz_f16_f32)
__device__ __forceinline__ unsigned cpk(float lo, float hi) {
    return __builtin_bit_cast(unsigned, __builtin_amdgcn_cvt_pkrtz(lo, hi));
}

// packed f16 relu via v_pk_max_f16
__device__ __forceinline__ unsigned relu2(unsigned a) {
    unsigned r;
    asm("v_pk_max_f16 %0, %1, %2" : "=v"(r) : "v"(a), "v"(0u));
    return r;
}

// f16-pair dot product with f32 accumulate: d = a.lo*b.lo + a.hi*b.hi + c
__device__ __forceinline__ float fdot2(unsigned a, unsigned b, float c) {
    float d;
    asm("v_dot2_f32_f16 %0, %1, %2, %3" : "=v"(d) : "v"(a), "v"(b), "v"(c));
    return d;
}

__device__ __forceinline__ __half2 bch2(unsigned u) {
    return __builtin_bit_cast(__half2, u);
}

// ---- main: block = 4 waves; wave wv owns feature f = (bx>>6)*4+wv,
//      rows [rg*512, rg*512+512), rg = bx&63. 8 chunks of 64 rows.
//      Tail: atomicAdd row-sums to logitacc; 32nd finisher per rg does
//      bias+sigmoid+store inline (threadfence-reduction pattern).
__global__ __launch_bounds__(256, 3)
void nam_main(const float* __restrict__ x,
              const float* __restrict__ w1, const float* __restrict__ b1,
              const float* __restrict__ b2, const float* __restrict__ w3,
              const float* __restrict__ b3,
              const float* __restrict__ w2,
              const float* __restrict__ bias,
              float* __restrict__ logitacc,
              unsigned* __restrict__ cnt,
              float* __restrict__ out)
{
    __shared__ float partial[4][512];    // 8KB
    __shared__ int lastFlag;

    const int tid  = threadIdx.x;
    const int lane = tid & 63;
    const int wv   = tid >> 6;           // 0..3
    const int l15  = lane & 15;
    const int quad = lane >> 4;
    const int rg   = blockIdx.x & 63;
    const int gf   = blockIdx.x >> 6;    // 0..31
    const int f    = gf * 4 + wv;
    const int rb   = rg * 512;

    // ---- per-wave resident tables ----
    // w2 A-fragments packed in-place from fp32 source (f16):
    // frag (gt,ks): elem j = w2[f][k=ks*32+quad*8+j][g=gt*16+l15]
    const float* w2f = w2 + (size_t)f * H_SZ * H_SZ;
    half8 wfrag[4][2];
    #pragma unroll
    for (int gt = 0; gt < 4; ++gt)
        #pragma unroll
        for (int ks = 0; ks < 2; ++ks) {
            const float* src = w2f + (ks * 32 + quad * 8) * H_SZ + gt * 16 + l15;
            U8 o;
            #pragma unroll
            for (int t = 0; t < 4; ++t)
                o.u[t] = pkh(src[(2 * t) * H_SZ], src[(2 * t + 1) * H_SZ]);
            wfrag[gt][ks] = o.v;
        }

    // w1/b1 as packed half2: element k = ks*32 + quad*8 + (2t, 2t+1)
    unsigned wk2[2][4], bk2[2][4];
    #pragma unroll
    for (int ks = 0; ks < 2; ++ks) {
        float wtmp[8], btmp[8];
        const float4* wq = (const float4*)(w1 + f * 64 + ks * 32 + quad * 8);
        const float4* bq = (const float4*)(b1 + f * 64 + ks * 32 + quad * 8);
        *(float4*)&wtmp[0] = wq[0]; *(float4*)&wtmp[4] = wq[1];
        *(float4*)&btmp[0] = bq[0]; *(float4*)&btmp[4] = bq[1];
        #pragma unroll
        for (int t = 0; t < 4; ++t) {
            wk2[ks][t] = pkh(wtmp[2 * t], wtmp[2 * t + 1]);
            bk2[ks][t] = pkh(btmp[2 * t], btmp[2 * t + 1]);
        }
    }

    // b2 as MFMA C operand quads; w3 as packed f16 pairs for fdot2:
    // pair p of tile gt covers g = gt*16 + quad*4 + {2p, 2p+1}
    floatx4 b2c[4];
    unsigned w3h[4][2];
    #pragma unroll
    for (int gt = 0; gt < 4; ++gt) {
        float4 bv  = *(const float4*)(b2 + f * 64 + gt * 16 + quad * 4);
        float4 wv3 = *(const float4*)(w3 + f * 64 + gt * 16 + quad * 4);
        b2c[gt] = floatx4{bv.x, bv.y, bv.z, bv.w};
        w3h[gt][0] = pkh(wv3.x, wv3.y);
        w3h[gt][1] = pkh(wv3.z, wv3.w);
    }
    const float b3f = b3[f];

    // ---- 8 chunks of 64 rows, software-pipelined x gather ----
    float xv = x[(size_t)(rb + lane) * F_SZ + f];   // chunk 0

    #pragma unroll 1
    for (int c = 0; c < 8; ++c) {
        float xvn;
        if (c < 7)
            xvn = x[(size_t)(rb + (c + 1) * 64 + lane) * F_SZ + f];

        // splat-pack x to half2 once, broadcast packed word per 16-row block
        unsigned xpk = __builtin_bit_cast(unsigned, __float2half2_rn(xv));
        unsigned xf[4];
        #pragma unroll
        for (int bt = 0; bt < 4; ++bt)
            xf[bt] = (unsigned)__shfl((int)xpk, bt * 16 + l15, 64);

        // h1 B-fragments in packed f16: B[k=quad*8+j][n=bt*16+l15]
        half8 hfrag[4][2];
        #pragma unroll
        for (int ks = 0; ks < 2; ++ks)
            #pragma unroll
            for (int bt = 0; bt < 4; ++bt) {
                U8 o;
                #pragma unroll
                for (int t = 0; t < 4; ++t) {
                    __half2 h = __hfma2(bch2(xf[bt]), bch2(wk2[ks][t]), bch2(bk2[ks][t]));
                    o.u[t] = relu2(__builtin_bit_cast(unsigned, h));
                }
                hfrag[bt][ks] = o.v;
            }

        // MFMA f16 (C = b2c direct, D != C) + fdot2 epilogue, prioritized.
        // Dual accumulators per bt (dep chain 8 -> 4 per stream).
        // D layout: g = gt*16+quad*4+i, n = bt*16+l15
        float ta[4] = {0.0f, 0.0f, 0.0f, 0.0f};
        float tb[4] = {0.0f, 0.0f, 0.0f, 0.0f};
        __builtin_amdgcn_s_setprio(1);
        #pragma unroll
        for (int gt = 0; gt < 4; ++gt)
            #pragma unroll
            for (int bt = 0; bt < 4; ++bt) {
                floatx4 acc = __builtin_amdgcn_mfma_f32_16x16x32_f16(
                    wfrag[gt][0], hfrag[bt][0], b2c[gt], 0, 0, 0);
                acc = __builtin_amdgcn_mfma_f32_16x16x32_f16(
                    wfrag[gt][1], hfrag[bt][1], acc, 0, 0, 0);
                unsigned p0 = relu2(cpk(acc[0], acc[1]));
                unsigned p1 = relu2(cpk(acc[2], acc[3]));
                ta[bt] = fdot2(p0, w3h[gt][0], ta[bt]);
                tb[bt] = fdot2(p1, w3h[gt][1], tb[bt]);
            }
        __builtin_amdgcn_s_setprio(0);

        // quad-reduce (row = bt*16 + l15), publish per-chunk rows
        float t[4];
        #pragma unroll
        for (int bt = 0; bt < 4; ++bt) {
            t[bt] = ta[bt] + tb[bt];
            t[bt] += __shfl_xor(t[bt], 16, 64);
            t[bt] += __shfl_xor(t[bt], 32, 64);
        }
        if (quad == 0) {
            #pragma unroll
            for (int bt = 0; bt < 4; ++bt)
                partial[wv][c * 64 + bt * 16 + l15] = t[bt] + b3f;
        }

        xv = xvn;
    }

    __syncthreads();

    // block reduce over the 4 features -> atomic accumulate into logitacc
    #pragma unroll
    for (int k = 0; k < 2; ++k) {
        int row = k * 256 + tid;
        float p = partial[0][row] + partial[1][row]
                + partial[2][row] + partial[3][row];
        atomicAdd(&logitacc[rb + row], p);
    }

    // completion: 32nd finisher per rg does bias+sigmoid+store inline
    __threadfence();
    __syncthreads();
    if (tid == 0) {
        unsigned old = __hip_atomic_fetch_add(&cnt[rg], 1u,
                           __ATOMIC_ACQ_REL, __HIP_MEMORY_SCOPE_AGENT);
        lastFlag = (old == 31u);
    }
    __syncthreads();

    if (lastFlag) {
        const float bsc = bias[0];
        #pragma unroll
        for (int k = 0; k < 2; ++k) {
            int row = k * 256 + tid;
            float s = __hip_atomic_load(&logitacc[rb + row],
                          __ATOMIC_ACQUIRE, __HIP_MEMORY_SCOPE_AGENT);
            s += bsc;
            float p = 1.0f / (1.0f + __expf(-s));
            ((float2*)out)[rb + row] = make_float2(1.0f - p, p);
        }
    }
}

extern "C" void kernel_launch(void* const* d_in, const int* in_sizes, int n_in,
                              void* d_out, int out_size, void* d_ws, size_t ws_size,
                              hipStream_t stream)
{
    const float* x    = (const float*)d_in[0];
    const float* w1   = (const float*)d_in[1];
    const float* b1   = (const float*)d_in[2];
    const float* w2   = (const float*)d_in[3];
    const float* b2   = (const float*)d_in[4];
    const float* w3   = (const float*)d_in[5];
    const float* b3   = (const float*)d_in[6];
    const float* bias = (const float*)d_in[7];
    float* out = (float*)d_out;

    float* logitacc = (float*)d_ws;                    // 128 KB
    unsigned* cnt   = (unsigned*)d_ws + B_SZ;          // 256 B

    hipMemsetAsync(d_ws, 0, B_SZ * sizeof(float) + 64 * sizeof(unsigned),
                   stream);

    nam_main<<<dim3(2048), dim3(256), 0, stream>>>(
        x, w1, b1, b2, w3, b3, w2, bias, logitacc, cnt, out);
}

// Round 20
// 115.243 us; speedup vs baseline: 2.5132x; 2.5132x over previous
//
#include <hip/hip_runtime.h>
#include <hip/hip_bf16.h>
#include <hip/hip_fp16.h>

// NAM_89739046683406: per-feature tiny MLP (B=32768, F=128, H=64)
// logit(b) = bias + sum_f [ relu(relu(x[b,f]*w1[f]+b1[f]) @ w2[f] + b2[f]) . w3[f] + b3[f] ]
// out = [1-sigmoid, sigmoid]
//
// R41 = EXACT resubmission of R37 -- the session-best verified kernel
// (113.94us total / ~48.8us main, absmax 0.00390625) -- restoring the
// record after R40's fused-atomic-finisher regressed (49 -> 227us main:
// device-scope fp32 atomics bypass the non-coherent per-XCD L2s; 1M
// atomicAdds serialize against HBM arbitration; MfmaUtil 29 -> 6%).
//
// FINAL session ledger (20 rounds, 124.7 -> 113.9us total, -21% main):
//   WINS (cumulative):
//   - R22: layer-1 in packed f16 (v_pk_fma/v_pk_max feed MFMA frags
//     directly) + f16 16x16x32 MFMA: -25% VALU -> -15% time.
//   - R33: fdot2 epilogue (cvt_pkrtz + pk_max + v_dot2_f32_f16): -4%.
//   - R37: s_setprio(1) around MFMA+fdot2 cluster (T5, barrier-free
//     phase-diverse waves): -3%.
//   CLOSED classes (direct evidence):
//   - Occupancy: LB(256,4) panic-spills (R24); plain LB(256) under-resides
//     (R26); per-bt high-occ loses (R27); 8-wave geometry under-resides
//     (R34). Peak = LB(256,3), 26%, non-monotonic.
//   - ILP-pipelining: unroll (R23) and named-dbuf pipeline (R35) regress.
//   - Chunk-size: 128-row soft-spills WRITE 4->5.85MB (R38; R27 confounded).
//   - x-path: per-lane gathers (R23), LDS staging (R25) -- no effect.
//   - Tail: [16][520] scatter neutral+conflicts (R28); [wv][row][quad]
//     scatter absmax-fails (R36). shfl_xor tail stands.
//   - MFMA-epilogue: 16x16x16 builtin NaN (R30); zero-padded 16x16x32
//     absmax 0.68 (R31). Fault not isolatable without debug visibility.
//   - fdot2 chain split: neutral (R39).
//   - Fused final dispatch: atomics catastrophic (R40).
//   Constraints: NO float-ext-vector arrays + __builtin_elementwise_*
//   (R17/R18); judge spills by FETCH/WRITE, not VGPR_Count.
// Regime: latency-bound plateau (HBM 5.5%, MfmaUtil 29%, VALU ~49) --
// NOT a hardware roofline; ~49us vs ~17us issue floor is dependency
// stall that 10 probe classes failed to close at 3 blocks/CU.

#define B_SZ 32768
#define F_SZ 128
#define H_SZ 64

typedef _Float16 half8 __attribute__((ext_vector_type(8)));  // f16 x8 (4 VGPR)
typedef float floatx4 __attribute__((ext_vector_type(4)));   // fp32 x4 acc

union U8 { half8 v; unsigned u[4]; };

// pack two fp32 -> half2 bits (RNE)
__device__ __forceinline__ unsigned pkh(float lo, float hi) {
    __half2 h = __float22half2_rn(make_float2(lo, hi));
    return __builtin_bit_cast(unsigned, h);
}

// pack two fp32 -> half2 bits (RTZ, single v_cvt_pkrtz_f16_f32)
__device__ __forceinline__ unsigned cpk(float lo, float hi) {
    return __builtin_bit_cast(unsigned, __builtin_amdgcn_cvt_pkrtz(lo, hi));
}

// packed f16 relu via v_pk_max_f16
__device__ __forceinline__ unsigned relu2(unsigned a) {
    unsigned r;
    asm("v_pk_max_f16 %0, %1, %2" : "=v"(r) : "v"(a), "v"(0u));
    return r;
}

// f16-pair dot product with f32 accumulate: d = a.lo*b.lo + a.hi*b.hi + c
__device__ __forceinline__ float fdot2(unsigned a, unsigned b, float c) {
    float d;
    asm("v_dot2_f32_f16 %0, %1, %2, %3" : "=v"(d) : "v"(a), "v"(b), "v"(c));
    return d;
}

__device__ __forceinline__ __half2 bch2(unsigned u) {
    return __builtin_bit_cast(__half2, u);
}

// ---- main: block = 4 waves; wave wv owns feature f = (bx>>6)*4+wv,
//      rows [rg*512, rg*512+512), rg = bx&63. 8 chunks of 64 rows.
//      Preamble packs w2[f] -> f16 A-fragments in registers.
//      Output: part[gf][rb..rb+512) plain store (sole writer).
__global__ __launch_bounds__(256, 3)
void nam_main(const float* __restrict__ x,
              const float* __restrict__ w1, const float* __restrict__ b1,
              const float* __restrict__ b2, const float* __restrict__ w3,
              const float* __restrict__ b3,
              const float* __restrict__ w2,
              float* __restrict__ part)
{
    __shared__ float partial[4][512];    // 8KB

    const int tid  = threadIdx.x;
    const int lane = tid & 63;
    const int wv   = tid >> 6;           // 0..3
    const int l15  = lane & 15;
    const int quad = lane >> 4;
    const int rg   = blockIdx.x & 63;
    const int gf   = blockIdx.x >> 6;    // 0..31
    const int f    = gf * 4 + wv;
    const int rb   = rg * 512;

    // ---- per-wave resident tables ----
    // w2 A-fragments packed in-place from fp32 source (f16):
    // frag (gt,ks): elem j = w2[f][k=ks*32+quad*8+j][g=gt*16+l15]
    const float* w2f = w2 + (size_t)f * H_SZ * H_SZ;
    half8 wfrag[4][2];
    #pragma unroll
    for (int gt = 0; gt < 4; ++gt)
        #pragma unroll
        for (int ks = 0; ks < 2; ++ks) {
            const float* src = w2f + (ks * 32 + quad * 8) * H_SZ + gt * 16 + l15;
            U8 o;
            #pragma unroll
            for (int t = 0; t < 4; ++t)
                o.u[t] = pkh(src[(2 * t) * H_SZ], src[(2 * t + 1) * H_SZ]);
            wfrag[gt][ks] = o.v;
        }

    // w1/b1 as packed half2: element k = ks*32 + quad*8 + (2t, 2t+1)
    unsigned wk2[2][4], bk2[2][4];
    #pragma unroll
    for (int ks = 0; ks < 2; ++ks) {
        float wtmp[8], btmp[8];
        const float4* wq = (const float4*)(w1 + f * 64 + ks * 32 + quad * 8);
        const float4* bq = (const float4*)(b1 + f * 64 + ks * 32 + quad * 8);
        *(float4*)&wtmp[0] = wq[0]; *(float4*)&wtmp[4] = wq[1];
        *(float4*)&btmp[0] = bq[0]; *(float4*)&btmp[4] = bq[1];
        #pragma unroll
        for (int t = 0; t < 4; ++t) {
            wk2[ks][t] = pkh(wtmp[2 * t], wtmp[2 * t + 1]);
            bk2[ks][t] = pkh(btmp[2 * t], btmp[2 * t + 1]);
        }
    }

    // b2 as MFMA C operand quads; w3 as packed f16 pairs for fdot2:
    // pair p of tile gt covers g = gt*16 + quad*4 + {2p, 2p+1}
    floatx4 b2c[4];
    unsigned w3h[4][2];
    #pragma unroll
    for (int gt = 0; gt < 4; ++gt) {
        float4 bv  = *(const float4*)(b2 + f * 64 + gt * 16 + quad * 4);
        float4 wv3 = *(const float4*)(w3 + f * 64 + gt * 16 + quad * 4);
        b2c[gt] = floatx4{bv.x, bv.y, bv.z, bv.w};
        w3h[gt][0] = pkh(wv3.x, wv3.y);
        w3h[gt][1] = pkh(wv3.z, wv3.w);
    }
    const float b3f = b3[f];

    // ---- 8 chunks of 64 rows, software-pipelined x gather ----
    float xv = x[(size_t)(rb + lane) * F_SZ + f];   // chunk 0

    #pragma unroll 1
    for (int c = 0; c < 8; ++c) {
        float xvn;
        if (c < 7)
            xvn = x[(size_t)(rb + (c + 1) * 64 + lane) * F_SZ + f];

        // splat-pack x to half2 once, broadcast packed word per 16-row block
        unsigned xpk = __builtin_bit_cast(unsigned, __float2half2_rn(xv));
        unsigned xf[4];
        #pragma unroll
        for (int bt = 0; bt < 4; ++bt)
            xf[bt] = (unsigned)__shfl((int)xpk, bt * 16 + l15, 64);

        // h1 B-fragments in packed f16: B[k=quad*8+j][n=bt*16+l15]
        half8 hfrag[4][2];
        #pragma unroll
        for (int ks = 0; ks < 2; ++ks)
            #pragma unroll
            for (int bt = 0; bt < 4; ++bt) {
                U8 o;
                #pragma unroll
                for (int t = 0; t < 4; ++t) {
                    __half2 h = __hfma2(bch2(xf[bt]), bch2(wk2[ks][t]), bch2(bk2[ks][t]));
                    o.u[t] = relu2(__builtin_bit_cast(unsigned, h));
                }
                hfrag[bt][ks] = o.v;
            }

        // MFMA f16 (C = b2c direct, D != C) + fdot2 epilogue, prioritized
        // (T5: waves here are phase-diverse -- no barriers in chunk loop).
        // D layout: g = gt*16 + quad*4 + i, n = bt*16 + l15
        float t[4] = {0.0f, 0.0f, 0.0f, 0.0f};
        __builtin_amdgcn_s_setprio(1);
        #pragma unroll
        for (int gt = 0; gt < 4; ++gt)
            #pragma unroll
            for (int bt = 0; bt < 4; ++bt) {
                floatx4 acc = __builtin_amdgcn_mfma_f32_16x16x32_f16(
                    wfrag[gt][0], hfrag[bt][0], b2c[gt], 0, 0, 0);
                acc = __builtin_amdgcn_mfma_f32_16x16x32_f16(
                    wfrag[gt][1], hfrag[bt][1], acc, 0, 0, 0);
                unsigned p0 = relu2(cpk(acc[0], acc[1]));
                unsigned p1 = relu2(cpk(acc[2], acc[3]));
                t[bt] = fdot2(p0, w3h[gt][0], t[bt]);
                t[bt] = fdot2(p1, w3h[gt][1], t[bt]);
            }
        __builtin_amdgcn_s_setprio(0);

        // quad-reduce (row = bt*16 + l15), publish per-chunk rows
        #pragma unroll
        for (int bt = 0; bt < 4; ++bt) {
            t[bt] += __shfl_xor(t[bt], 16, 64);
            t[bt] += __shfl_xor(t[bt], 32, 64);
        }
        if (quad == 0) {
            #pragma unroll
            for (int bt = 0; bt < 4; ++bt)
                partial[wv][c * 64 + bt * 16 + l15] = t[bt] + b3f;
        }

        xv = xvn;
    }

    __syncthreads();

    // block reduce over the 4 features -> plain coalesced store (sole writer)
    #pragma unroll
    for (int k = 0; k < 2; ++k) {
        int row = k * 256 + tid;
        float p = partial[0][row] + partial[1][row]
                + partial[2][row] + partial[3][row];
        part[(size_t)gf * B_SZ + rb + row] = p;
    }
}

// ---- final: 1 row/thread, sum 32 gf-partials + bias + sigmoid ----
__global__ __launch_bounds__(256)
void nam_final(const float* __restrict__ part, const float* __restrict__ bias,
               float* __restrict__ out)
{
    int b = blockIdx.x * 256 + threadIdx.x;
    float s = bias[0];
    #pragma unroll
    for (int gf = 0; gf < 32; ++gf)
        s += part[(size_t)gf * B_SZ + b];
    float p = 1.0f / (1.0f + __expf(-s));
    ((float2*)out)[b] = make_float2(1.0f - p, p);
}

extern "C" void kernel_launch(void* const* d_in, const int* in_sizes, int n_in,
                              void* d_out, int out_size, void* d_ws, size_t ws_size,
                              hipStream_t stream)
{
    const float* x    = (const float*)d_in[0];
    const float* w1   = (const float*)d_in[1];
    const float* b1   = (const float*)d_in[2];
    const float* w2   = (const float*)d_in[3];
    const float* b2   = (const float*)d_in[4];
    const float* w3   = (const float*)d_in[5];
    const float* b3   = (const float*)d_in[6];
    const float* bias = (const float*)d_in[7];
    float* out = (float*)d_out;

    float* part = (float*)d_ws;   // part[32][B_SZ], 4MB

    nam_main<<<dim3(2048), dim3(256), 0, stream>>>(
        x, w1, b1, b2, w3, b3, w2, part);
    nam_final<<<dim3(B_SZ / 256), dim3(256), 0, stream>>>(part, bias, out);
}

// Round 21
// 114.357 us; speedup vs baseline: 2.5327x; 1.0077x over previous
//
#include <hip/hip_runtime.h>
#include <hip/hip_bf16.h>
#include <hip/hip_fp16.h>

// NAM_89739046683406: per-feature tiny MLP (B=32768, F=128, H=64)
// logit(b) = bias + sum_f [ relu(relu(x[b,f]*w1[f]+b1[f]) @ w2[f] + b2[f]) . w3[f] + b3[f] ]
// out = [1-sigmoid, sigmoid]
//
// R43 = R37/R41 FINAL -- the session-best verified kernel, held as the
// terminal submission (3x reproduced: 113.9 / 115.9 / 115.2 us total,
// main 47.2-49.6 us, absmax 0.00390625).
//
// SESSION SUMMARY (21 rounds, 124.7 -> 113.9us total, main -21%):
//   WINS (cumulative):
//   - R22: layer-1 in packed f16 (v_pk_fma/v_pk_max feed MFMA B-frags
//     directly; w1/b1/w2 held as f16) + f16 16x16x32 MFMA: -15% time.
//   - R33: fdot2 epilogue (cvt_pkrtz + pk_max + v_dot2_f32_f16): -4%.
//   - R37: s_setprio(1) around the MFMA+fdot2 cluster (T5 -- barrier-free
//     chunk loop gives phase-diverse waves): -3%.
//   CLOSED classes (all by direct experiment):
//   - Occupancy: LB(256,4) panic-spills (R24); plain LB(256) under-resides
//     (R26); per-bt restructure loses even at occ 34% (R27); 8-wave
//     geometry under-resides (R34). LB(256,3) + 4-wave + grid 2048 = peak.
//   - ILP-pipelining: unroll x2 (R23) and named-dbuf pipeline (R35) both
//     regress +15-20% -- hipcc re-serializes through live buffers.
//   - Chunk-size 128: soft-spill, WRITE 4->5.85MB at flat VGPR (R38).
//   - x-path: per-lane gathers (R23) and LDS tile staging (R25) no effect.
//   - Tail: [16][520] scatter neutral + 524k bank conflicts (R28);
//     [wv][row][quad] scatter absmax 0.283 (R36).
//   - MFMA-epilogue: 16x16x16f16 builtin NaN (R30); zero-padded 16x16x32
//     absmax 0.68 (R31). Needs debug visibility the harness lacks.
//   - fdot2 dual-accumulator chain split: neutral (R39).
//   - Fused final via device atomics: 49 -> 227us main (R40 -- cross-XCD
//     fp32 atomics bypass non-coherent L2s and serialize at HBM).
//   Constraints: NO float-ext-vector arrays + __builtin_elementwise_*
//   (R17/R18); judge spills by FETCH/WRITE counters, not VGPR_Count.
// REGIME: structural latency plateau, NOT a hardware roofline (HBM 5.6%,
// MfmaUtil 28%, VALUBusy 49%). Per-chunk serial dep chain ~1.1k cy vs
// ~650 issue cy at ~2-3 interleaved waves/SIMD; every removal/overlap/
// occupancy lever is closed above. Path past it: MFMA-epilogue concept
// (requires intermediate-value debugging) or sub-source scheduling control.

#define B_SZ 32768
#define F_SZ 128
#define H_SZ 64

typedef _Float16 half8 __attribute__((ext_vector_type(8)));  // f16 x8 (4 VGPR)
typedef float floatx4 __attribute__((ext_vector_type(4)));   // fp32 x4 acc

union U8 { half8 v; unsigned u[4]; };

// pack two fp32 -> half2 bits (RNE)
__device__ __forceinline__ unsigned pkh(float lo, float hi) {
    __half2 h = __float22half2_rn(make_float2(lo, hi));
    return __builtin_bit_cast(unsigned, h);
}

// pack two fp32 -> half2 bits (RTZ, single v_cvt_pkrtz_f16_f32)
__device__ __forceinline__ unsigned cpk(float lo, float hi) {
    return __builtin_bit_cast(unsigned, __builtin_amdgcn_cvt_pkrtz(lo, hi));
}

// packed f16 relu via v_pk_max_f16
__device__ __forceinline__ unsigned relu2(unsigned a) {
    unsigned r;
    asm("v_pk_max_f16 %0, %1, %2" : "=v"(r) : "v"(a), "v"(0u));
    return r;
}

// f16-pair dot product with f32 accumulate: d = a.lo*b.lo + a.hi*b.hi + c
__device__ __forceinline__ float fdot2(unsigned a, unsigned b, float c) {
    float d;
    asm("v_dot2_f32_f16 %0, %1, %2, %3" : "=v"(d) : "v"(a), "v"(b), "v"(c));
    return d;
}

__device__ __forceinline__ __half2 bch2(unsigned u) {
    return __builtin_bit_cast(__half2, u);
}

// ---- main: block = 4 waves; wave wv owns feature f = (bx>>6)*4+wv,
//      rows [rg*512, rg*512+512), rg = bx&63. 8 chunks of 64 rows.
//      Preamble packs w2[f] -> f16 A-fragments in registers.
//      Output: part[gf][rb..rb+512) plain store (sole writer).
__global__ __launch_bounds__(256, 3)
void nam_main(const float* __restrict__ x,
              const float* __restrict__ w1, const float* __restrict__ b1,
              const float* __restrict__ b2, const float* __restrict__ w3,
              const float* __restrict__ b3,
              const float* __restrict__ w2,
              float* __restrict__ part)
{
    __shared__ float partial[4][512];    // 8KB

    const int tid  = threadIdx.x;
    const int lane = tid & 63;
    const int wv   = tid >> 6;           // 0..3
    const int l15  = lane & 15;
    const int quad = lane >> 4;
    const int rg   = blockIdx.x & 63;
    const int gf   = blockIdx.x >> 6;    // 0..31
    const int f    = gf * 4 + wv;
    const int rb   = rg * 512;

    // ---- per-wave resident tables ----
    // w2 A-fragments packed in-place from fp32 source (f16):
    // frag (gt,ks): elem j = w2[f][k=ks*32+quad*8+j][g=gt*16+l15]
    const float* w2f = w2 + (size_t)f * H_SZ * H_SZ;
    half8 wfrag[4][2];
    #pragma unroll
    for (int gt = 0; gt < 4; ++gt)
        #pragma unroll
        for (int ks = 0; ks < 2; ++ks) {
            const float* src = w2f + (ks * 32 + quad * 8) * H_SZ + gt * 16 + l15;
            U8 o;
            #pragma unroll
            for (int t = 0; t < 4; ++t)
                o.u[t] = pkh(src[(2 * t) * H_SZ], src[(2 * t + 1) * H_SZ]);
            wfrag[gt][ks] = o.v;
        }

    // w1/b1 as packed half2: element k = ks*32 + quad*8 + (2t, 2t+1)
    unsigned wk2[2][4], bk2[2][4];
    #pragma unroll
    for (int ks = 0; ks < 2; ++ks) {
        float wtmp[8], btmp[8];
        const float4* wq = (const float4*)(w1 + f * 64 + ks * 32 + quad * 8);
        const float4* bq = (const float4*)(b1 + f * 64 + ks * 32 + quad * 8);
        *(float4*)&wtmp[0] = wq[0]; *(float4*)&wtmp[4] = wq[1];
        *(float4*)&btmp[0] = bq[0]; *(float4*)&btmp[4] = bq[1];
        #pragma unroll
        for (int t = 0; t < 4; ++t) {
            wk2[ks][t] = pkh(wtmp[2 * t], wtmp[2 * t + 1]);
            bk2[ks][t] = pkh(btmp[2 * t], btmp[2 * t + 1]);
        }
    }

    // b2 as MFMA C operand quads; w3 as packed f16 pairs for fdot2:
    // pair p of tile gt covers g = gt*16 + quad*4 + {2p, 2p+1}
    floatx4 b2c[4];
    unsigned w3h[4][2];
    #pragma unroll
    for (int gt = 0; gt < 4; ++gt) {
        float4 bv  = *(const float4*)(b2 + f * 64 + gt * 16 + quad * 4);
        float4 wv3 = *(const float4*)(w3 + f * 64 + gt * 16 + quad * 4);
        b2c[gt] = floatx4{bv.x, bv.y, bv.z, bv.w};
        w3h[gt][0] = pkh(wv3.x, wv3.y);
        w3h[gt][1] = pkh(wv3.z, wv3.w);
    }
    const float b3f = b3[f];

    // ---- 8 chunks of 64 rows, software-pipelined x gather ----
    float xv = x[(size_t)(rb + lane) * F_SZ + f];   // chunk 0

    #pragma unroll 1
    for (int c = 0; c < 8; ++c) {
        float xvn;
        if (c < 7)
            xvn = x[(size_t)(rb + (c + 1) * 64 + lane) * F_SZ + f];

        // splat-pack x to half2 once, broadcast packed word per 16-row block
        unsigned xpk = __builtin_bit_cast(unsigned, __float2half2_rn(xv));
        unsigned xf[4];
        #pragma unroll
        for (int bt = 0; bt < 4; ++bt)
            xf[bt] = (unsigned)__shfl((int)xpk, bt * 16 + l15, 64);

        // h1 B-fragments in packed f16: B[k=quad*8+j][n=bt*16+l15]
        half8 hfrag[4][2];
        #pragma unroll
        for (int ks = 0; ks < 2; ++ks)
            #pragma unroll
            for (int bt = 0; bt < 4; ++bt) {
                U8 o;
                #pragma unroll
                for (int t = 0; t < 4; ++t) {
                    __half2 h = __hfma2(bch2(xf[bt]), bch2(wk2[ks][t]), bch2(bk2[ks][t]));
                    o.u[t] = relu2(__builtin_bit_cast(unsigned, h));
                }
                hfrag[bt][ks] = o.v;
            }

        // MFMA f16 (C = b2c direct, D != C) + fdot2 epilogue, prioritized
        // (T5: waves here are phase-diverse -- no barriers in chunk loop).
        // D layout: g = gt*16 + quad*4 + i, n = bt*16 + l15
        float t[4] = {0.0f, 0.0f, 0.0f, 0.0f};
        __builtin_amdgcn_s_setprio(1);
        #pragma unroll
        for (int gt = 0; gt < 4; ++gt)
            #pragma unroll
            for (int bt = 0; bt < 4; ++bt) {
                floatx4 acc = __builtin_amdgcn_mfma_f32_16x16x32_f16(
                    wfrag[gt][0], hfrag[bt][0], b2c[gt], 0, 0, 0);
                acc = __builtin_amdgcn_mfma_f32_16x16x32_f16(
                    wfrag[gt][1], hfrag[bt][1], acc, 0, 0, 0);
                unsigned p0 = relu2(cpk(acc[0], acc[1]));
                unsigned p1 = relu2(cpk(acc[2], acc[3]));
                t[bt] = fdot2(p0, w3h[gt][0], t[bt]);
                t[bt] = fdot2(p1, w3h[gt][1], t[bt]);
            }
        __builtin_amdgcn_s_setprio(0);

        // quad-reduce (row = bt*16 + l15), publish per-chunk rows
        #pragma unroll
        for (int bt = 0; bt < 4; ++bt) {
            t[bt] += __shfl_xor(t[bt], 16, 64);
            t[bt] += __shfl_xor(t[bt], 32, 64);
        }
        if (quad == 0) {
            #pragma unroll
            for (int bt = 0; bt < 4; ++bt)
                partial[wv][c * 64 + bt * 16 + l15] = t[bt] + b3f;
        }

        xv = xvn;
    }

    __syncthreads();

    // block reduce over the 4 features -> plain coalesced store (sole writer)
    #pragma unroll
    for (int k = 0; k < 2; ++k) {
        int row = k * 256 + tid;
        float p = partial[0][row] + partial[1][row]
                + partial[2][row] + partial[3][row];
        part[(size_t)gf * B_SZ + rb + row] = p;
    }
}

// ---- final: 1 row/thread, sum 32 gf-partials + bias + sigmoid ----
__global__ __launch_bounds__(256)
void nam_final(const float* __restrict__ part, const float* __restrict__ bias,
               float* __restrict__ out)
{
    int b = blockIdx.x * 256 + threadIdx.x;
    float s = bias[0];
    #pragma unroll
    for (int gf = 0; gf < 32; ++gf)
        s += part[(size_t)gf * B_SZ + b];
    float p = 1.0f / (1.0f + __expf(-s));
    ((float2*)out)[b] = make_float2(1.0f - p, p);
}

extern "C" void kernel_launch(void* const* d_in, const int* in_sizes, int n_in,
                              void* d_out, int out_size, void* d_ws, size_t ws_size,
                              hipStream_t stream)
{
    const float* x    = (const float*)d_in[0];
    const float* w1   = (const float*)d_in[1];
    const float* b1   = (const float*)d_in[2];
    const float* w2   = (const float*)d_in[3];
    const float* b2   = (const float*)d_in[4];
    const float* w3   = (const float*)d_in[5];
    const float* b3   = (const float*)d_in[6];
    const float* bias = (const float*)d_in[7];
    float* out = (float*)d_out;

    float* part = (float*)d_ws;   // part[32][B_SZ], 4MB

    nam_main<<<dim3(2048), dim3(256), 0, stream>>>(
        x, w1, b1, b2, w3, b3, w2, part);
    nam_final<<<dim3(B_SZ / 256), dim3(256), 0, stream>>>(part, bias, out);
}